// Round 5
// baseline (1004.977 us; speedup 1.0000x reference)
//
#include <hip/hip_runtime.h>

// Problem constants
#define N_ROWS 65536   // 32*2048 rows
#define DDIM   64
#define KCODES 2048
#define NB     128     // rows per block (argmin kernel)
#define CHUNK  256     // codes per LDS chunk
#define NCHUNK (KCODES / CHUNK)
#define TAU    0.05f   // top-2 gap threshold for fp64 refinement

// d_out layout (float32, concatenated in reference return order)
#define Q_OFF    ((size_t)0)
#define ENC_OFF  ((size_t)N_ROWS * DDIM)                 // 4194304
#define IDX_OFF  (ENC_OFF + (size_t)N_ROWS * KCODES)     // 138412032
#define LOSS_OFF (IDX_OFF + (size_t)N_ROWS)              // 138477568
#define INV_ND (1.0f / ((float)N_ROWS * (float)DDIM))

// d_ws layout (bytes) — R2-proven footprint, nothing past 794624:
//   [0, 524288)        : bf16 B image, 8 chunks x { hi[256][64], lo[256][64] } shorts
//                        (k index stored XOR-swizzled: kk = k ^ ((code&7)<<3))
//   [524288, 532480)   : esq, 2048 floats
//   [532480, 794624)   : flags, 65536 ints
#define WS_ESQ_OFF   (524288)
#define WS_FLAGS_OFF (532480)

typedef __attribute__((ext_vector_type(8))) short short8;
typedef __attribute__((ext_vector_type(4))) float f32x4;

__device__ __forceinline__ unsigned short f2bf(float f) {
    unsigned u = __float_as_uint(f);
    u += 0x7FFFu + ((u >> 16) & 1u);
    return (unsigned short)(u >> 16);
}
__device__ __forceinline__ float bf2f(unsigned short h) {
    return __uint_as_float(((unsigned)h) << 16);
}

// Split embeddings into bf16 hi/lo (swizzled) + ||e||^2 + zero loss slot.
__global__ void vq_prep(const float* __restrict__ emb, char* __restrict__ ws,
                        float* __restrict__ out) {
    int t = blockIdx.x * 256 + threadIdx.x;        // [0, 131072)
    int code = t & (KCODES - 1);
    int d    = t >> 11;
    float v = emb[(size_t)d * KCODES + code];
    unsigned short hi = f2bf(v);
    unsigned short lo = f2bf(v - bf2f(hi));
    int ch = code >> 8;
    int lc = code & 255;
    int kk = d ^ ((code & 7) << 3);
    short* base = (short*)ws + (size_t)ch * 32768 + lc * 64 + kk;
    base[0]     = (short)hi;
    base[16384] = (short)lo;
    if (t < KCODES) {
        float s = 0.f;
        for (int dd = 0; dd < DDIM; ++dd) {
            float e = emb[(size_t)dd * KCODES + t];
            s += e * e;
        }
        ((float*)(ws + WS_ESQ_OFF))[t] = s;
    }
    if (t == 0) out[LOSS_OFF] = 0.f;
}

// Pure compute: 3-term bf16-split MFMA distances -> per-row top-2 -> idx + flags.
// No large stores -> chunk barriers drain nothing.
__launch_bounds__(256, 2)
__global__ void vq_argmin(const float* __restrict__ x, const char* __restrict__ ws,
                          float* __restrict__ out) {
    __shared__ __align__(16) short Bs[32768];   // 64 KB: hi[256][64] then lo[256][64]
    const int tid = threadIdx.x;
    const int l = tid & 63, w = tid >> 6;
    const int q = l >> 4, c = l & 15;
    const int r0 = blockIdx.x * NB;
    const float* esq = (const float*)(ws + WS_ESQ_OFF);
    int*   flags = (int*)(ws + WS_FLAGS_OFF);

    // A fragments: this wave's 32 rows, bf16 hi/lo, in registers.
    // A-operand layout: lane holds A[m = l&15][k = q*8 + j].
    short8 ah0[2], ah1[2], al0[2], al1[2];
    #pragma unroll
    for (int rt = 0; rt < 2; ++rt) {
        int row = r0 + w * 32 + rt * 16 + c;
        const float4* xr = (const float4*)(x + (size_t)row * DDIM);
        float4 f0 = xr[q * 2],     f1 = xr[q * 2 + 1];
        float4 f2 = xr[8 + q * 2], f3 = xr[8 + q * 2 + 1];
        float a0[8] = {f0.x,f0.y,f0.z,f0.w,f1.x,f1.y,f1.z,f1.w};
        float a1[8] = {f2.x,f2.y,f2.z,f2.w,f3.x,f3.y,f3.z,f3.w};
        #pragma unroll
        for (int j = 0; j < 8; ++j) {
            unsigned short h0 = f2bf(a0[j]);
            ah0[rt][j] = (short)h0;
            al0[rt][j] = (short)f2bf(a0[j] - bf2f(h0));
            unsigned short h1 = f2bf(a1[j]);
            ah1[rt][j] = (short)h1;
            al1[rt][j] = (short)f2bf(a1[j] - bf2f(h1));
        }
    }

    float m1[8], m2[8]; int i1[8];
    #pragma unroll
    for (int s = 0; s < 8; ++s) { m1[s] = 3.4e38f; m2[s] = 3.4e38f; i1[s] = 0; }

    for (int ch = 0; ch < NCHUNK; ++ch) {
        const int kc = ch * CHUNK;
        __syncthreads();
        {
            const int4* g4 = (const int4*)(ws + (size_t)ch * 65536);
            int4* s4 = (int4*)Bs;
            #pragma unroll
            for (int i = 0; i < 16; ++i) s4[i * 256 + tid] = g4[i * 256 + tid];
        }
        __syncthreads();

        const int swz = (c & 7) << 3;
        for (int t = 0; t < 16; ++t) {
            int codeL = t * 16 + c;
            const short* ph = Bs + codeL * 64;
            const short* pl = ph + 16384;
            int k0 = (q * 8) ^ swz;
            int k1 = (32 + q * 8) ^ swz;
            short8 bh0 = *(const short8*)(ph + k0);
            short8 bh1 = *(const short8*)(ph + k1);
            short8 bl0 = *(const short8*)(pl + k0);
            short8 bl1 = *(const short8*)(pl + k1);
            int   kidx = kc + t * 16 + c;
            float eq   = esq[kidx];
            #pragma unroll
            for (int rt = 0; rt < 2; ++rt) {
                f32x4 acc = {0.f, 0.f, 0.f, 0.f};
                acc = __builtin_amdgcn_mfma_f32_16x16x32_bf16(ah0[rt], bh0, acc, 0, 0, 0);
                acc = __builtin_amdgcn_mfma_f32_16x16x32_bf16(ah1[rt], bh1, acc, 0, 0, 0);
                acc = __builtin_amdgcn_mfma_f32_16x16x32_bf16(ah0[rt], bl0, acc, 0, 0, 0);
                acc = __builtin_amdgcn_mfma_f32_16x16x32_bf16(ah1[rt], bl1, acc, 0, 0, 0);
                acc = __builtin_amdgcn_mfma_f32_16x16x32_bf16(al0[rt], bh0, acc, 0, 0, 0);
                acc = __builtin_amdgcn_mfma_f32_16x16x32_bf16(al1[rt], bh1, acc, 0, 0, 0);
                #pragma unroll
                for (int g = 0; g < 4; ++g) {
                    float dist = fmaf(-2.f, acc[g], eq);   // ||x||^2 omitted (row-const)
                    int s = rt * 4 + g;
                    bool better = dist < m1[s];
                    m2[s] = fminf(m2[s], fmaxf(m1[s], dist));
                    m1[s] = fminf(m1[s], dist);
                    i1[s] = better ? kidx : i1[s];
                }
            }
        }
    }

    __syncthreads();   // Bs dead -> reuse for reduction
    float* red = (float*)Bs;                  // [128 rows][16 cols][3]: m1, idx, m2

    // C/D layout: col = l&15, row = q*4 + reg  [m89]
    #pragma unroll
    for (int rt = 0; rt < 2; ++rt)
        #pragma unroll
        for (int g = 0; g < 4; ++g) {
            int lrow = w * 32 + rt * 16 + q * 4 + g;
            float* p = red + (size_t)(lrow * 16 + c) * 3;
            p[0] = m1[rt * 4 + g];
            p[1] = (float)i1[rt * 4 + g];
            p[2] = m2[rt * 4 + g];
        }
    __syncthreads();

    if (tid < NB) {
        int row = tid;
        const float* p = red + (size_t)row * 48;
        float gm1 = 3.4e38f; int gi1 = 0x7fffffff; int wt = -1;
        for (int t = 0; t < 16; ++t) {
            float v  = p[t * 3 + 0];
            int   iv = (int)p[t * 3 + 1];
            if (v < gm1 || (v == gm1 && iv < gi1)) { gm1 = v; gi1 = iv; wt = t; }
        }
        float gm2 = 3.4e38f;
        for (int t = 0; t < 16; ++t) {
            float cand = (t == wt) ? p[t * 3 + 2] : p[t * 3 + 0];
            gm2 = fminf(gm2, cand);
        }
        int gr = r0 + row;
        out[IDX_OFF + gr] = (float)gi1;
        flags[gr] = (gm2 - gm1 < TAU) ? 1 : 0;
    }
}

// Pure streaming write: one-hot rows, quantized rows, loss. Normal stores.
// Reads indices back from d_out (cross-kernel d_out read is R2-proven).
__global__ void vq_write(const float* __restrict__ x, const float* __restrict__ emb,
                         float* __restrict__ out) {
    const int tid  = threadIdx.x;
    const int row0 = blockIdx.x * 16;
    __shared__ float lred[4];
    __shared__ int   idxS[16];

    if (tid < 16) idxS[tid] = (int)out[IDX_OFF + row0 + tid];
    __syncthreads();

    // Quantized rows + loss partial: thread t -> row row0+(t>>4), dims (t&15)*4..+3
    int r  = tid >> 4;
    int d4 = (tid & 15) << 2;
    int rowq = row0 + r;
    int idxq = idxS[r];
    float4 qv;
    qv.x = emb[(size_t)(d4 + 0) * KCODES + idxq];
    qv.y = emb[(size_t)(d4 + 1) * KCODES + idxq];
    qv.z = emb[(size_t)(d4 + 2) * KCODES + idxq];
    qv.w = emb[(size_t)(d4 + 3) * KCODES + idxq];
    *(float4*)(out + Q_OFF + (size_t)rowq * DDIM + d4) = qv;
    float4 xv = *(const float4*)(x + (size_t)rowq * DDIM + d4);
    float dx = qv.x - xv.x, dy = qv.y - xv.y, dz = qv.z - xv.z, dw = qv.w - xv.w;
    float lpart = dx * dx + dy * dy + dz * dz + dw * dw;

    // One-hot: per row, 256 threads x 2 float4 = 8 KB; 1.0 inserted via compares.
    const int base = tid << 3;
    #pragma unroll 4
    for (int rr = 0; rr < 16; ++rr) {
        int row = row0 + rr;
        int idx = idxS[rr];
        float4 v0, v1;
        v0.x = (base + 0 == idx) ? 1.f : 0.f;
        v0.y = (base + 1 == idx) ? 1.f : 0.f;
        v0.z = (base + 2 == idx) ? 1.f : 0.f;
        v0.w = (base + 3 == idx) ? 1.f : 0.f;
        v1.x = (base + 4 == idx) ? 1.f : 0.f;
        v1.y = (base + 5 == idx) ? 1.f : 0.f;
        v1.z = (base + 6 == idx) ? 1.f : 0.f;
        v1.w = (base + 7 == idx) ? 1.f : 0.f;
        float* p = out + ENC_OFF + (size_t)row * KCODES + base;
        *(float4*)p       = v0;
        *(float4*)(p + 4) = v1;
    }

    // Block loss reduction -> one atomic
    #pragma unroll
    for (int o = 32; o > 0; o >>= 1) lpart += __shfl_down(lpart, o);
    if ((tid & 63) == 0) lred[tid >> 6] = lpart;
    __syncthreads();
    if (tid == 0)
        atomicAdd(out + LOSS_OFF, (lred[0] + lred[1] + lred[2] + lred[3]) * INV_ND);
}

// Exact fp64 argmin for rows whose top-2 gap was below TAU. Runs last.
__global__ void vq_refine(const float* __restrict__ x, const float* __restrict__ emb,
                          const int* __restrict__ flags, float* __restrict__ out) {
    const int lane = threadIdx.x & 63;
    const int wid  = threadIdx.x >> 6;
    for (int rr = 0; rr < 8; ++rr) {
        int row = (blockIdx.x * 4 + wid) * 8 + rr;
        if (flags[row] == 0) continue;                 // wave-uniform
        const float* xr = x + (size_t)row * DDIM;
        double best = 1e300; int bidx = 0x7fffffff;
        for (int k = lane; k < KCODES; k += 64) {
            double s = 0.0, ee = 0.0;
            for (int d = 0; d < DDIM; ++d) {
                double e = (double)emb[(size_t)d * KCODES + k];
                s  = fma((double)xr[d], e, s);
                ee = fma(e, e, ee);
            }
            double dist = ee - 2.0 * s;
            if (dist < best) { best = dist; bidx = k; }
        }
        #pragma unroll
        for (int o = 32; o > 0; o >>= 1) {
            double ob = __shfl_down(best, o);
            int    oi = __shfl_down(bidx, o);
            if (ob < best || (ob == best && oi < bidx)) { best = ob; bidx = oi; }
        }
        bidx = __shfl(bidx, 0);
        int oldIdx = (int)out[IDX_OFF + row];
        if (bidx == oldIdx) continue;
        if (lane == 0) {
            out[IDX_OFF + row] = (float)bidx;
            out[ENC_OFF + (size_t)row * KCODES + oldIdx] = 0.f;
            out[ENC_OFF + (size_t)row * KCODES + bidx]   = 1.f;
        }
        float eN = emb[(size_t)lane * KCODES + bidx];
        float eO = emb[(size_t)lane * KCODES + oldIdx];
        float xv = xr[lane];
        out[Q_OFF + (size_t)row * DDIM + lane] = eN;
        float dn = eN - xv, dod = eO - xv;
        float delta = dn * dn - dod * dod;
        #pragma unroll
        for (int o = 32; o > 0; o >>= 1) delta += __shfl_down(delta, o);
        if (lane == 0) atomicAdd(out + LOSS_OFF, delta * INV_ND);
    }
}

extern "C" void kernel_launch(void* const* d_in, const int* in_sizes, int n_in,
                              void* d_out, int out_size, void* d_ws, size_t ws_size,
                              hipStream_t stream) {
    const float* x   = (const float*)d_in[0];   // [65536, 64]
    const float* emb = (const float*)d_in[1];   // [64, 2048]
    float* out   = (float*)d_out;
    char*  ws    = (char*)d_ws;
    int*   flags = (int*)(ws + WS_FLAGS_OFF);
    hipLaunchKernelGGL(vq_prep,   dim3(512),          dim3(256), 0, stream, emb, ws, out);
    hipLaunchKernelGGL(vq_argmin, dim3(N_ROWS / NB),  dim3(256), 0, stream, x, ws, out);
    hipLaunchKernelGGL(vq_write,  dim3(N_ROWS / 16),  dim3(256), 0, stream, x, emb, out);
    hipLaunchKernelGGL(vq_refine, dim3(N_ROWS / 32),  dim3(256), 0, stream, x, emb, flags, out);
}

// Round 6
// 876.383 us; speedup vs baseline: 1.1467x; 1.1467x over previous
//
#include <hip/hip_runtime.h>

// Problem constants
#define N_ROWS 65536   // 32*2048 rows
#define DDIM   64
#define KCODES 2048
#define NB     128     // rows per block (argmin kernel)
#define CHUNK  256     // codes per LDS chunk
#define NCHUNK (KCODES / CHUNK)
#define TAU    0.05f   // top-2 gap threshold for fp64 refinement

// d_out layout (float32, concatenated in reference return order)
#define Q_OFF    ((size_t)0)
#define ENC_OFF  ((size_t)N_ROWS * DDIM)                 // 4194304
#define IDX_OFF  (ENC_OFF + (size_t)N_ROWS * KCODES)     // 138412032
#define LOSS_OFF (IDX_OFF + (size_t)N_ROWS)              // 138477568
#define INV_ND (1.0f / ((float)N_ROWS * (float)DDIM))

// d_ws layout (bytes) — R2/R5-proven footprint, nothing past 794624:
//   [0, 524288)        : bf16 B image, 8 chunks x { hi[256][64], lo[256][64] } shorts
//                        (k index stored XOR-swizzled: kk = k ^ ((code&7)<<3))
//   [524288, 532480)   : esq, 2048 floats
//   [532480, 794624)   : flags, 65536 ints
#define WS_ESQ_OFF   (524288)
#define WS_FLAGS_OFF (532480)

typedef __attribute__((ext_vector_type(8))) short short8;
typedef __attribute__((ext_vector_type(4))) float f32x4;

__device__ __forceinline__ unsigned short f2bf(float f) {
    unsigned u = __float_as_uint(f);
    u += 0x7FFFu + ((u >> 16) & 1u);
    return (unsigned short)(u >> 16);
}
__device__ __forceinline__ float bf2f(unsigned short h) {
    return __uint_as_float(((unsigned)h) << 16);
}

// Split embeddings into bf16 hi/lo (swizzled) + ||e||^2 + zero loss slot.
__global__ void vq_prep(const float* __restrict__ emb, char* __restrict__ ws,
                        float* __restrict__ out) {
    int t = blockIdx.x * 256 + threadIdx.x;        // [0, 131072)
    int code = t & (KCODES - 1);
    int d    = t >> 11;
    float v = emb[(size_t)d * KCODES + code];
    unsigned short hi = f2bf(v);
    unsigned short lo = f2bf(v - bf2f(hi));
    int ch = code >> 8;
    int lc = code & 255;
    int kk = d ^ ((code & 7) << 3);
    short* base = (short*)ws + (size_t)ch * 32768 + lc * 64 + kk;
    base[0]     = (short)hi;
    base[16384] = (short)lo;
    if (t < KCODES) {
        float s = 0.f;
        for (int dd = 0; dd < DDIM; ++dd) {
            float e = emb[(size_t)dd * KCODES + t];
            s += e * e;
        }
        ((float*)(ws + WS_ESQ_OFF))[t] = s;
    }
    if (t == 0) out[LOSS_OFF] = 0.f;
}

// Pure compute: 3-term bf16-split MFMA distances -> per-row top-2 -> idx + flags.
__launch_bounds__(256, 2)
__global__ void vq_argmin(const float* __restrict__ x, const char* __restrict__ ws,
                          float* __restrict__ out) {
    __shared__ __align__(16) short Bs[32768];   // 64 KB: hi[256][64] then lo[256][64]
    const int tid = threadIdx.x;
    const int l = tid & 63, w = tid >> 6;
    const int q = l >> 4, c = l & 15;
    const int r0 = blockIdx.x * NB;
    const float* esq = (const float*)(ws + WS_ESQ_OFF);
    int*   flags = (int*)(ws + WS_FLAGS_OFF);

    // A fragments: this wave's 32 rows, bf16 hi/lo, in registers.
    // A-operand layout: lane holds A[m = l&15][k = q*8 + j].
    short8 ah0[2], ah1[2], al0[2], al1[2];
    #pragma unroll
    for (int rt = 0; rt < 2; ++rt) {
        int row = r0 + w * 32 + rt * 16 + c;
        const float4* xr = (const float4*)(x + (size_t)row * DDIM);
        float4 f0 = xr[q * 2],     f1 = xr[q * 2 + 1];
        float4 f2 = xr[8 + q * 2], f3 = xr[8 + q * 2 + 1];
        float a0[8] = {f0.x,f0.y,f0.z,f0.w,f1.x,f1.y,f1.z,f1.w};
        float a1[8] = {f2.x,f2.y,f2.z,f2.w,f3.x,f3.y,f3.z,f3.w};
        #pragma unroll
        for (int j = 0; j < 8; ++j) {
            unsigned short h0 = f2bf(a0[j]);
            ah0[rt][j] = (short)h0;
            al0[rt][j] = (short)f2bf(a0[j] - bf2f(h0));
            unsigned short h1 = f2bf(a1[j]);
            ah1[rt][j] = (short)h1;
            al1[rt][j] = (short)f2bf(a1[j] - bf2f(h1));
        }
    }

    float m1[8], m2[8]; int i1[8];
    #pragma unroll
    for (int s = 0; s < 8; ++s) { m1[s] = 3.4e38f; m2[s] = 3.4e38f; i1[s] = 0; }

    for (int ch = 0; ch < NCHUNK; ++ch) {
        const int kc = ch * CHUNK;
        __syncthreads();
        {
            const int4* g4 = (const int4*)(ws + (size_t)ch * 65536);
            int4* s4 = (int4*)Bs;
            #pragma unroll
            for (int i = 0; i < 16; ++i) s4[i * 256 + tid] = g4[i * 256 + tid];
        }
        __syncthreads();

        const int swz = (c & 7) << 3;
        for (int t = 0; t < 16; ++t) {
            int codeL = t * 16 + c;
            const short* ph = Bs + codeL * 64;
            const short* pl = ph + 16384;
            int k0 = (q * 8) ^ swz;
            int k1 = (32 + q * 8) ^ swz;
            short8 bh0 = *(const short8*)(ph + k0);
            short8 bh1 = *(const short8*)(ph + k1);
            short8 bl0 = *(const short8*)(pl + k0);
            short8 bl1 = *(const short8*)(pl + k1);
            int   kidx = kc + t * 16 + c;
            float eq   = esq[kidx];
            #pragma unroll
            for (int rt = 0; rt < 2; ++rt) {
                f32x4 acc = {0.f, 0.f, 0.f, 0.f};
                acc = __builtin_amdgcn_mfma_f32_16x16x32_bf16(ah0[rt], bh0, acc, 0, 0, 0);
                acc = __builtin_amdgcn_mfma_f32_16x16x32_bf16(ah1[rt], bh1, acc, 0, 0, 0);
                acc = __builtin_amdgcn_mfma_f32_16x16x32_bf16(ah0[rt], bl0, acc, 0, 0, 0);
                acc = __builtin_amdgcn_mfma_f32_16x16x32_bf16(ah1[rt], bl1, acc, 0, 0, 0);
                acc = __builtin_amdgcn_mfma_f32_16x16x32_bf16(al0[rt], bh0, acc, 0, 0, 0);
                acc = __builtin_amdgcn_mfma_f32_16x16x32_bf16(al1[rt], bh1, acc, 0, 0, 0);
                #pragma unroll
                for (int g = 0; g < 4; ++g) {
                    float dist = fmaf(-2.f, acc[g], eq);   // ||x||^2 omitted (row-const)
                    int s = rt * 4 + g;
                    bool better = dist < m1[s];
                    m2[s] = fminf(m2[s], fmaxf(m1[s], dist));
                    m1[s] = fminf(m1[s], dist);
                    i1[s] = better ? kidx : i1[s];
                }
            }
        }
    }

    __syncthreads();   // Bs dead -> reuse for reduction
    float* red = (float*)Bs;                  // [128 rows][16 cols][3]: m1, idx, m2

    // C/D layout: col = l&15, row = q*4 + reg  [m89]
    #pragma unroll
    for (int rt = 0; rt < 2; ++rt)
        #pragma unroll
        for (int g = 0; g < 4; ++g) {
            int lrow = w * 32 + rt * 16 + q * 4 + g;
            float* p = red + (size_t)(lrow * 16 + c) * 3;
            p[0] = m1[rt * 4 + g];
            p[1] = (float)i1[rt * 4 + g];
            p[2] = m2[rt * 4 + g];
        }
    __syncthreads();

    if (tid < NB) {
        int row = tid;
        const float* p = red + (size_t)row * 48;
        float gm1 = 3.4e38f; int gi1 = 0x7fffffff; int wt = -1;
        for (int t = 0; t < 16; ++t) {
            float v  = p[t * 3 + 0];
            int   iv = (int)p[t * 3 + 1];
            if (v < gm1 || (v == gm1 && iv < gi1)) { gm1 = v; gi1 = iv; wt = t; }
        }
        float gm2 = 3.4e38f;
        for (int t = 0; t < 16; ++t) {
            float cand = (t == wt) ? p[t * 3 + 2] : p[t * 3 + 0];
            gm2 = fminf(gm2, cand);
        }
        int gr = r0 + row;
        out[IDX_OFF + gr] = (float)gi1;
        flags[gr] = (gm2 - gm1 < TAU) ? 1 : 0;
    }
}

// Pure streaming write: one-hot rows, quantized rows, loss.
// 512 blocks x 128 rows. Fully-coalesced stores: each wave-store is a
// contiguous 1 KB (16 B/lane). One loss atomic per block (512 total, R2-proven).
__launch_bounds__(256, 2)
__global__ void vq_write(const float* __restrict__ x, const float* __restrict__ emb,
                         float* __restrict__ out) {
    const int tid  = threadIdx.x;
    const int row0 = blockIdx.x * 128;
    __shared__ float lred[4];
    __shared__ int   idxS[128];

    if (tid < 128) idxS[tid] = (int)out[IDX_OFF + row0 + tid];
    __syncthreads();

    // Quantized rows + loss partials: lanes 0..15 cover one row contiguously.
    float lpart = 0.f;
    for (int i = tid; i < 128 * 16; i += 256) {
        int row = i >> 4;
        int d4  = (i & 15) << 2;
        int idx = idxS[row];
        int gr  = row0 + row;
        float4 qv;
        qv.x = emb[(size_t)(d4 + 0) * KCODES + idx];
        qv.y = emb[(size_t)(d4 + 1) * KCODES + idx];
        qv.z = emb[(size_t)(d4 + 2) * KCODES + idx];
        qv.w = emb[(size_t)(d4 + 3) * KCODES + idx];
        *(float4*)(out + Q_OFF + (size_t)gr * DDIM + d4) = qv;
        float4 xv = *(const float4*)(x + (size_t)gr * DDIM + d4);
        float dx = qv.x - xv.x, dy = qv.y - xv.y, dz = qv.z - xv.z, dw = qv.w - xv.w;
        lpart += dx * dx + dy * dy + dz * dz + dw * dw;
    }

    // One-hot: row = 512 float4 slots; thread t owns slots t and t+256.
    // Per wave-store: contiguous 1 KB (full 64 B lines per instruction).
    const int b0 = tid << 2;
    const int b1 = (tid + 256) << 2;
    #pragma unroll 4
    for (int rr = 0; rr < 128; ++rr) {
        int idx = idxS[rr];
        float* p = out + ENC_OFF + (size_t)(row0 + rr) * KCODES;
        float4 v0, v1;
        v0.x = (b0 + 0 == idx) ? 1.f : 0.f;
        v0.y = (b0 + 1 == idx) ? 1.f : 0.f;
        v0.z = (b0 + 2 == idx) ? 1.f : 0.f;
        v0.w = (b0 + 3 == idx) ? 1.f : 0.f;
        v1.x = (b1 + 0 == idx) ? 1.f : 0.f;
        v1.y = (b1 + 1 == idx) ? 1.f : 0.f;
        v1.z = (b1 + 2 == idx) ? 1.f : 0.f;
        v1.w = (b1 + 3 == idx) ? 1.f : 0.f;
        *(float4*)(p + b0) = v0;
        *(float4*)(p + b1) = v1;
    }

    // Block loss reduction -> one atomic (512 total)
    #pragma unroll
    for (int o = 32; o > 0; o >>= 1) lpart += __shfl_down(lpart, o);
    if ((tid & 63) == 0) lred[tid >> 6] = lpart;
    __syncthreads();
    if (tid == 0)
        atomicAdd(out + LOSS_OFF, (lred[0] + lred[1] + lred[2] + lred[3]) * INV_ND);
}

// Exact fp64 argmin for rows whose top-2 gap was below TAU. Runs last.
__global__ void vq_refine(const float* __restrict__ x, const float* __restrict__ emb,
                          const int* __restrict__ flags, float* __restrict__ out) {
    const int lane = threadIdx.x & 63;
    const int wid  = threadIdx.x >> 6;
    for (int rr = 0; rr < 8; ++rr) {
        int row = (blockIdx.x * 4 + wid) * 8 + rr;
        if (flags[row] == 0) continue;                 // wave-uniform
        const float* xr = x + (size_t)row * DDIM;
        double best = 1e300; int bidx = 0x7fffffff;
        for (int k = lane; k < KCODES; k += 64) {
            double s = 0.0, ee = 0.0;
            for (int d = 0; d < DDIM; ++d) {
                double e = (double)emb[(size_t)d * KCODES + k];
                s  = fma((double)xr[d], e, s);
                ee = fma(e, e, ee);
            }
            double dist = ee - 2.0 * s;
            if (dist < best) { best = dist; bidx = k; }
        }
        #pragma unroll
        for (int o = 32; o > 0; o >>= 1) {
            double ob = __shfl_down(best, o);
            int    oi = __shfl_down(bidx, o);
            if (ob < best || (ob == best && oi < bidx)) { best = ob; bidx = oi; }
        }
        bidx = __shfl(bidx, 0);
        int oldIdx = (int)out[IDX_OFF + row];
        if (bidx == oldIdx) continue;
        if (lane == 0) {
            out[IDX_OFF + row] = (float)bidx;
            out[ENC_OFF + (size_t)row * KCODES + oldIdx] = 0.f;
            out[ENC_OFF + (size_t)row * KCODES + bidx]   = 1.f;
        }
        float eN = emb[(size_t)lane * KCODES + bidx];
        float eO = emb[(size_t)lane * KCODES + oldIdx];
        float xv = xr[lane];
        out[Q_OFF + (size_t)row * DDIM + lane] = eN;
        float dn = eN - xv, dod = eO - xv;
        float delta = dn * dn - dod * dod;
        #pragma unroll
        for (int o = 32; o > 0; o >>= 1) delta += __shfl_down(delta, o);
        if (lane == 0) atomicAdd(out + LOSS_OFF, delta * INV_ND);
    }
}

extern "C" void kernel_launch(void* const* d_in, const int* in_sizes, int n_in,
                              void* d_out, int out_size, void* d_ws, size_t ws_size,
                              hipStream_t stream) {
    const float* x   = (const float*)d_in[0];   // [65536, 64]
    const float* emb = (const float*)d_in[1];   // [64, 2048]
    float* out   = (float*)d_out;
    char*  ws    = (char*)d_ws;
    int*   flags = (int*)(ws + WS_FLAGS_OFF);
    hipLaunchKernelGGL(vq_prep,   dim3(512),          dim3(256), 0, stream, emb, ws, out);
    hipLaunchKernelGGL(vq_argmin, dim3(N_ROWS / NB),  dim3(256), 0, stream, x, ws, out);
    hipLaunchKernelGGL(vq_write,  dim3(N_ROWS / 128), dim3(256), 0, stream, x, emb, out);
    hipLaunchKernelGGL(vq_refine, dim3(N_ROWS / 32),  dim3(256), 0, stream, x, emb, flags, out);
}